// Round 3
// baseline (221.146 us; speedup 1.0000x reference)
//
#include <hip/hip_runtime.h>

// LRN_19705309954750 — cross-channel banded LRN on [B=64, C=128, H=56, W=56] fp32.
// y[c] = sum_{d=-8..8} x[(c+d)%128]^2 ; out = x * (y*ALPHA/17 + 1)^(-0.75)
//
// R7 post-mortem: sched_barrier did NOT keep the 48-load batch live (VGPR=80,
// not ~116) — third structure where the compiler sinks register-destination
// loads to cut pressure. Also: R6's 3x-amplified run hit 6.2 TB/s cache-side
// (= fabric ceiling), while low-amp R5/R7 ran 3.4-3.6 TB/s latency-bound.
// R8: make the pipeline compiler-proof. Async global_load_lds (NO dest
// register -> nothing to sink; tracked only by vmcnt) into a 26-slot LDS
// ring of channel planes. Per step: issue plane c+16, compute/store output c,
// then hand-counted s_waitcnt vmcnt(15) before the window-slide reads
// (7 loads + 8 stores allowed outstanding -> 7 KB/wave of loads permanently
// in flight; x6 waves/CU = 42 KB/CU >> latency-BW product ~22 KB).
// Slot indices are compile-time after full unroll -> ds_read_b128 with
// immediate offsets. Tail loads clamp to plane 71's own slot (bit-identical
// rewrite) so vmcnt arithmetic stays static. Amp = 88/64 = 1.375x ->
// cache-side ~245 MB -> ~39 us floor at the 6.3 TB/s fabric ceiling.

#define HW4 784                  // float4 columns per plane (56*56/4)
#define BSTR (128 * HW4)         // float4 stride per batch image
#define NCOL4 (64 * HW4)         // 50176 float4 columns total
#define SEGC 64                  // channels per segment (NSEG=2)
#define RING 26                  // LDS ring slots (live span = 25)
#define DQ 16                    // prefetch distance (planes ahead)

typedef __attribute__((address_space(3))) unsigned int lds_u32;
typedef __attribute__((address_space(1))) const unsigned int glb_u32;

__device__ __forceinline__ float pow_m075(float t) {
    // t in [1, ~1.01]; HW log2 + exp2 (~1 ulp each) — far inside 0.108 absmax
    return __builtin_amdgcn_exp2f(-0.75f * __builtin_amdgcn_logf(t));
}

__global__ __launch_bounds__(64) void lrn_kernel(const float4* __restrict__ x,
                                                 float4* __restrict__ out) {
    const float kAlphaOverR = 0.001f / 17.0f;

    __shared__ float4 ring[RING][64];        // 26 KB: plane slot = 64 lanes x 16 B

    const int lane = threadIdx.x;
    const int col4 = blockIdx.x * 64 + lane;     // [0, NCOL4)
    const int b    = col4 / HW4;
    const int hw4  = col4 - b * HW4;
    const int c0   = blockIdx.y * SEGC;

    const float4* bx = x + (size_t)b * BSTR + hw4;    // channel stride = HW4
    float4*       bo = out + (size_t)b * BSTR + hw4;

    // ---- prologue: async-load planes -8..15 (segment-local) into slots 0..23
#pragma unroll
    for (int p = -8; p < DQ; ++p) {
        const int ch = (c0 + p) & 127;
        __builtin_amdgcn_global_load_lds((glb_u32*)(bx + (size_t)ch * HW4),
                                         (lds_u32*)&ring[p + 8][0], 16, 0, 0);
    }
    // need planes -8..8 (first 17 of 24 loads) resident: <=7 outstanding
    asm volatile("s_waitcnt vmcnt(7)" ::: "memory");

    // ---- initial window sum for output channel 0 (slots 0..16)
    float sx = 0.f, sy = 0.f, sz = 0.f, sw = 0.f;
#pragma unroll
    for (int j = 0; j < 17; ++j) {
        const float4 v = ring[j][lane];
        sx = fmaf(v.x, v.x, sx);
        sy = fmaf(v.y, v.y, sy);
        sz = fmaf(v.z, v.z, sz);
        sw = fmaf(v.w, v.w, sw);
    }

    // ---- main loop: fully unrolled, all ring offsets are immediates
#pragma unroll
    for (int c = 0; c < SEGC; ++c) {
        // 1. issue async load of plane c+DQ (clamped: tail rewrites plane 71's
        //    own slot with identical bits, keeping the vmcnt count static)
        const int pl = (c + DQ <= SEGC + 7) ? (c + DQ) : (SEGC + 7);
        const int ch = (c0 + pl) & 127;
        __builtin_amdgcn_global_load_lds((glb_u32*)(bx + (size_t)ch * HW4),
                                         (lds_u32*)&ring[(pl + 8) % RING][0], 16, 0, 0);

        // 2. numerator plane c (resident since step c-1's wait covered c+8)
        const float4 xc = ring[(c + 8) % RING][lane];
        float4 o;
        o.x = xc.x * pow_m075(fmaf(sx, kAlphaOverR, 1.0f));
        o.y = xc.y * pow_m075(fmaf(sy, kAlphaOverR, 1.0f));
        o.z = xc.z * pow_m075(fmaf(sz, kAlphaOverR, 1.0f));
        o.w = xc.w * pow_m075(fmaf(sw, kAlphaOverR, 1.0f));
        bo[(size_t)(c0 + c) * HW4] = o;

        // 3. slide window: need plane c+9 resident. It was issued at step c-7;
        //    since then: 7 loads + 8 stores = 15 vm-ops (steady state).
        if (c < SEGC - 1) {
            if (c < 7) asm volatile("s_waitcnt vmcnt(8)" ::: "memory");
            else       asm volatile("s_waitcnt vmcnt(15)" ::: "memory");
            const float4 a = ring[(c + 17) % RING][lane];   // plane c+9
            const float4 d = ring[c % RING][lane];          // plane c-8
            sx += a.x * a.x - d.x * d.x;
            sy += a.y * a.y - d.y * d.y;
            sz += a.z * a.z - d.z * d.z;
            sw += a.w * a.w - d.w * d.w;
        }
    }
}

extern "C" void kernel_launch(void* const* d_in, const int* in_sizes, int n_in,
                              void* d_out, int out_size, void* d_ws, size_t ws_size,
                              hipStream_t stream) {
    const float4* x = (const float4*)d_in[0];   // [64,128,56,56] fp32
    // d_in[1] (inhiMat) is a constant circulant band — computed analytically, unused.
    float4* out = (float4*)d_out;

    // 784 column-tiles x 2 channel-segments, 64-thread (1-wave) blocks.
    // 1568 blocks = 6.1/CU (LDS 26 KB -> 6 resident); latency hidden by
    // 7 async loads in flight per wave, not by occupancy.
    dim3 grid(NCOL4 / 64, 128 / SEGC);
    lrn_kernel<<<grid, 64, 0, stream>>>(x, out);
}

// Round 4
// 207.208 us; speedup vs baseline: 1.0673x; 1.0673x over previous
//
#include <hip/hip_runtime.h>

// LRN_19705309954750 — cross-channel banded LRN on [B=64, C=128, H=56, W=56] fp32.
// y[c] = sum_{d=-8..8} x[(c+d)%128]^2 ; out = x * (y*ALPHA/17 + 1)^(-0.75)
//
// R8 post-mortem: global_load_lds + ds_read made the COMPILER insert its own
// s_waitcnt vmcnt(0) before every dependent ds_read (it can't prove which LDS
// slot the async load writes) -> full queue drain per step, pipeline depth 0.
// 98us, 1.7 TB/s. Evidence so far: amp-3x R6 hit the 6.2 TB/s fabric ceiling;
// all low-amp variants stall at ~2.5 TB/s HBM with ~1 load in flight per wave
// and <=16 wg/CU residency from 64-thread blocks.
// R9: attack waves x in-flight-bytes directly, in registers (no LDS hazard):
//   (1) 256-thread blocks -> escape the 16-wg/CU cap; 1568 blocks x 4 waves
//       = 24.5 waves/CU resident.
//   (2) LA=2 source-level lookahead: iter i loads plane i+11, first consumed
//       at iter i+2 (slide) / i+11 (numerator). The NATURAL schedule has 2-3
//       loads in flight; the compiler would have to actively sink to break it.
//   (3) __launch_bounds__(256,6): 84-VGPR budget (ring 19xfloat2=38 + ~25
//       overhead fits with slack -> no pressure-driven sinking, no spill),
//       6 waves/SIMD = 24 waves/CU cap >= the 24.5 offered.
// Amp = 51/32 = 1.59x -> cache-side ~266 MB -> ~42 us floor at 6.3 TB/s.

#define HW2 1568                 // float2 columns per plane (56*56/2)
#define BSTR (128 * HW2)         // float2 stride per batch image
#define NCOL2 (64 * HW2)         // 100352 float2 columns
#define NSEG 4
#define SEGC (128 / NSEG)        // 32 channels per thread
#define RINGN 19                 // 17-wide window + LA=2 lookahead
#define LA 2

__device__ __forceinline__ float pow_m075(float t) {
    // t in [1, ~1.01]; HW log2 + exp2 (~1 ulp each) — far inside 0.108 absmax
    return __builtin_amdgcn_exp2f(-0.75f * __builtin_amdgcn_logf(t));
}

__global__ __launch_bounds__(256, 6) void lrn_kernel(const float2* __restrict__ x,
                                                     float2* __restrict__ out) {
    const float kAlphaOverR = 0.001f / 17.0f;

    const int col = blockIdx.x * 256 + threadIdx.x;   // [0, NCOL2)
    const int b   = col / HW2;
    const int hw2 = col - b * HW2;
    const int c0  = blockIdx.y * SEGC;

    const float2* base = x + (size_t)b * BSTR + hw2;    // channel stride = HW2
    float2* obase      = out + (size_t)b * BSTR + hw2;

    // Ring slot(p) = (p+8) mod 19 for plane p (segment-relative channel).
    // Prologue: planes -8..10 into slots 0..18.
    float2 r[RINGN];
#pragma unroll
    for (int p = -8; p <= 8 + LA; ++p) {
        const int ch = (c0 + p) & 127;
        r[p + 8] = base[(size_t)ch * HW2];
    }

    // Window sum for output channel 0: planes -8..8 (slots 0..16).
    float sx = 0.f, sy = 0.f;
#pragma unroll
    for (int j = 0; j < 17; ++j) {
        sx = fmaf(r[j].x, r[j].x, sx);
        sy = fmaf(r[j].y, r[j].y, sy);
    }

    // Fully unrolled: all ring indices compile-time.
#pragma unroll
    for (int i = 0; i < SEGC; ++i) {
        const int s_out = i % RINGN;            // plane i-8: last use this iter
        const float2 vout = r[s_out];           // read BEFORE slot is reloaded

        // Lookahead load: plane i+9+LA lands in the slot plane i-8 vacates.
        // First consumed at iter i+LA -> 2-3 loads naturally in flight.
        if (i + 9 + LA <= SEGC + 7) {
            const int ch = (c0 + i + 9 + LA) & 127;
            r[s_out] = base[(size_t)ch * HW2];
        }

        const float2 xc = r[(i + 8) % RINGN];   // plane i (numerator)
        float2 o;
        o.x = xc.x * pow_m075(fmaf(sx, kAlphaOverR, 1.0f));
        o.y = xc.y * pow_m075(fmaf(sy, kAlphaOverR, 1.0f));
        obase[(size_t)(c0 + i) * HW2] = o;

        // Slide window for iter i+1: +plane(i+9)^2 -plane(i-8)^2.
        // (At i=SEGC-1 this reads a stale slot; result is never used.)
        const float2 a = r[(i + 17) % RINGN];   // plane i+9
        sx += a.x * a.x - vout.x * vout.x;
        sy += a.y * a.y - vout.y * vout.y;
    }
}

extern "C" void kernel_launch(void* const* d_in, const int* in_sizes, int n_in,
                              void* d_out, int out_size, void* d_ws, size_t ws_size,
                              hipStream_t stream) {
    const float2* x = (const float2*)d_in[0];   // [64,128,56,56] fp32
    // d_in[1] (inhiMat) is a constant circulant band — computed analytically, unused.
    float2* out = (float2*)d_out;

    // 392 column-blocks x 4 channel-segments, 256-thread (4-wave) blocks:
    // 1568 blocks = 6.1/CU, 24.5 waves/CU resident (past the 16-wg/CU cap
    // that 64-thread blocks were hitting).
    dim3 grid(NCOL2 / 256, NSEG);
    lrn_kernel<<<grid, 256, 0, stream>>>(x, out);
}

// Round 5
// 183.565 us; speedup vs baseline: 1.2047x; 1.1288x over previous
//
#include <hip/hip_runtime.h>

// LRN_19705309954750 — cross-channel banded LRN on [B=64, C=128, H=56, W=56] fp32.
// y[c] = sum_{d=-8..8} x[(c+d)%128]^2 ; out = x * (y*ALPHA/17 + 1)^(-0.75)
//
// R9 post-mortem: VGPR=40 proves the 19-slot reg ring never existed; WRITE_SIZE
// 1.375x (137984 KB) + FETCH +28 MB = scratch traffic. Four rounds show the
// compiler always defeats register-destination load pipelining here (sinks or
// spills to minimize pressure -> MLP~1-2, ~2.5 TB/s plateau).
// R10: canonical LDS staging. Channels wrap mod 128, so staging ALL 128 planes
// of a column tile needs ZERO halo -> amp 1.0 both directions (206 MB total,
// 32.7 us floor). Block = 256 thr, tile = 32 float4 cols, LDS [128][32] f4 =
// 64 KB -> 2 blocks/CU. Staging: 64 global_load_lds (16/wave, 2 planes/inst,
// uniform LDS dest + per-lane src) -> 16 KB/wave in flight BY CONSTRUCTION
// (no dest regs to sink), ONE vmcnt(0)+barrier per block (not per step — the
// R8 mistake). Compute: thread = (col, 16 ch), running sums + 3 ds_read_b128
// per channel, no ring, ~30 VGPR. Inter-block skew overlaps compute (~1 us,
// LDS-bound) with the co-resident block's staging (HBM-bound).

#define HW4 784                  // float4 columns per plane (56*56/4)
#define CSTR HW4                 // float4 stride: channel plane
#define BSTR4 (128 * HW4)        // float4 stride: batch image
#define NCOL4 (64 * HW4)         // 50176 float4 columns total
#define TILE 32                  // float4 columns staged per block
#define NBLK (NCOL4 / TILE)      // 1568 blocks

typedef __attribute__((address_space(3))) unsigned int lds_u32;
typedef __attribute__((address_space(1))) const unsigned int glb_u32;

__device__ __forceinline__ float pow_m075(float t) {
    // t in [1, ~1.01]; HW log2 + exp2 (~1 ulp each) — far inside 0.108 absmax
    return __builtin_amdgcn_exp2f(-0.75f * __builtin_amdgcn_logf(t));
}

__global__ __launch_bounds__(256) void lrn_kernel(const float4* __restrict__ x,
                                                  float4* __restrict__ out) {
    const float kAlphaOverR = 0.001f / 17.0f;

    __shared__ float4 lds[128 * TILE];     // 64 KB: LDS[p*TILE + c] = plane p, col c

    const int tid  = threadIdx.x;
    const int lane = tid & 63;
    const int wave = tid >> 6;             // 0..3

    // ---- stage all 128 planes: wave w issues insts q = w*16 .. w*16+15,
    //      inst q stages planes {2q, 2q+1} (lanes 0-31 -> 2q, lanes 32-63 -> 2q+1)
    {
        const int cl    = lane & 31;                   // col within tile
        const int hi    = lane >> 5;                   // plane parity
        const int col4g = blockIdx.x * TILE + cl;      // global float4 column
        const int b     = col4g / HW4;
        const int hw4   = col4g - b * HW4;
        const float4* src0 = x + (size_t)b * BSTR4 + hw4 + (size_t)hi * CSTR;
#pragma unroll
        for (int j = 0; j < 16; ++j) {
            const int q = wave * 16 + j;               // plane pair index
            __builtin_amdgcn_global_load_lds((glb_u32*)(src0 + (size_t)q * (2 * CSTR)),
                                             (lds_u32*)&lds[q * 64], 16, 0, 0);
        }
    }
    asm volatile("s_waitcnt vmcnt(0)" ::: "memory");   // drain ONCE per block
    __syncthreads();

    // ---- compute: thread -> column (tid&31), 16 channels from ch0
    const int c   = tid & 31;
    const int ch0 = (tid >> 5) * 16;                   // 0,16,...,112

    const int col4g = blockIdx.x * TILE + c;
    const int b     = col4g / HW4;
    const int hw4   = col4g - b * HW4;
    float4* obase   = out + (size_t)b * BSTR4 + hw4;

    // initial window sum: planes ch0-8 .. ch0+8 (mod 128)
    float sx = 0.f, sy = 0.f, sz = 0.f, sw = 0.f;
#pragma unroll
    for (int j = -8; j <= 8; ++j) {
        const float4 v = lds[((ch0 + j) & 127) * TILE + c];
        sx = fmaf(v.x, v.x, sx);
        sy = fmaf(v.y, v.y, sy);
        sz = fmaf(v.z, v.z, sz);
        sw = fmaf(v.w, v.w, sw);
    }

#pragma unroll
    for (int i = 0; i < 16; ++i) {
        const int ch = ch0 + i;                        // <= 127, never wraps
        const float4 xc = lds[ch * TILE + c];          // numerator plane
        float4 o;
        o.x = xc.x * pow_m075(fmaf(sx, kAlphaOverR, 1.0f));
        o.y = xc.y * pow_m075(fmaf(sy, kAlphaOverR, 1.0f));
        o.z = xc.z * pow_m075(fmaf(sz, kAlphaOverR, 1.0f));
        o.w = xc.w * pow_m075(fmaf(sw, kAlphaOverR, 1.0f));
        obase[(size_t)ch * CSTR] = o;

        if (i < 15) {                                  // slide window mod 128
            const float4 a = lds[((ch + 9) & 127) * TILE + c];
            const float4 d = lds[((ch - 8) & 127) * TILE + c];
            sx += a.x * a.x - d.x * d.x;
            sy += a.y * a.y - d.y * d.y;
            sz += a.z * a.z - d.z * d.z;
            sw += a.w * a.w - d.w * d.w;
        }
    }
}

extern "C" void kernel_launch(void* const* d_in, const int* in_sizes, int n_in,
                              void* d_out, int out_size, void* d_ws, size_t ws_size,
                              hipStream_t stream) {
    const float4* x = (const float4*)d_in[0];   // [64,128,56,56] fp32
    // d_in[1] (inhiMat) is a constant circulant band — computed analytically, unused.
    float4* out = (float4*)d_out;

    // 1568 blocks x 256 threads; 64 KB LDS -> 2 blocks/CU, 6.1 block-slots/CU.
    // Every input byte read from HBM exactly once (no halo: channel wrap is
    // inside the staged 128 planes), every output written once.
    dim3 grid(NBLK);
    lrn_kernel<<<grid, 256, 0, stream>>>(x, out);
}

// Round 6
// 183.101 us; speedup vs baseline: 1.2078x; 1.0025x over previous
//
#include <hip/hip_runtime.h>

// LRN_19705309954750 — cross-channel banded LRN on [B=64, C=128, H=56, W=56] fp32.
// y[c] = sum_{d=-8..8} x[(c+d)%128]^2 ; out = x * (y*ALPHA/17 + 1)^(-0.75)
//
// R10 post-mortem: structure works (WRITE back to 100352 KB, FETCH 50 MB —
// input L3-resident, amp 1.0 confirmed) and 64us is best-yet, but 64 KB LDS
// -> only 2 blocks/CU (Occupancy 16%). The single-shot convoy has no
// intra-block overlap by design; with 2 slots/CU the phases align and HBM
// idles ~2/3 of the time (staging should be ~16us of the 64us measured).
// R11: same canonical structure, 2.5x more slots. TILE=16 cols -> 32 KB LDS
// -> 5 blocks/CU (160 KB exactly), 3136 blocks, 20 waves/CU. Five
// desynchronized blocks keep 2-3 staging at any instant (~64-96 KB/CU in
// flight continuously). Compute phase halves too (8 ch/thread, 40 ds_reads).
// 784 = 49*16 so 16-col tiles never straddle a batch boundary.

#define HW4 784                  // float4 columns per plane (56*56/4)
#define CSTR HW4                 // float4 stride: channel plane
#define BSTR4 (128 * HW4)        // float4 stride: batch image
#define NCOL4 (64 * HW4)         // 50176 float4 columns total
#define TILE 16                  // float4 columns staged per block
#define NBLK (NCOL4 / TILE)      // 3136 blocks

typedef __attribute__((address_space(3))) unsigned int lds_u32;
typedef __attribute__((address_space(1))) const unsigned int glb_u32;

__device__ __forceinline__ float pow_m075(float t) {
    // t in [1, ~1.01]; HW log2 + exp2 (~1 ulp each) — far inside 0.108 absmax
    return __builtin_amdgcn_exp2f(-0.75f * __builtin_amdgcn_logf(t));
}

__global__ __launch_bounds__(256, 5) void lrn_kernel(const float4* __restrict__ x,
                                                     float4* __restrict__ out) {
    const float kAlphaOverR = 0.001f / 17.0f;

    __shared__ float4 lds[128 * TILE];     // 32 KB: lds[p*TILE + c] = plane p, col c

    const int tid  = threadIdx.x;
    const int lane = tid & 63;
    const int wave = tid >> 6;             // 0..3

    // ---- stage all 128 planes: 32 insts total, 8 per wave.
    //      inst q writes lds bytes [q*1024, q*1024+1024) = planes 4q..4q+3,
    //      lane l -> plane 4q + (l>>4), col l&15 (dest = uniform + lane*16 ✓)
    {
        const int cl    = lane & 15;                   // col within tile
        const int pp    = lane >> 4;                   // plane sub-index 0..3
        const int col4g = blockIdx.x * TILE + cl;      // global float4 column
        const int b     = col4g / HW4;
        const int hw4   = col4g - b * HW4;
        const float4* src0 = x + (size_t)b * BSTR4 + hw4 + (size_t)pp * CSTR;
#pragma unroll
        for (int j = 0; j < 8; ++j) {
            const int q = wave * 8 + j;                // plane-quad index 0..31
            __builtin_amdgcn_global_load_lds((glb_u32*)(src0 + (size_t)q * (4 * CSTR)),
                                             (lds_u32*)&lds[q * 64], 16, 0, 0);
        }
    }
    asm volatile("s_waitcnt vmcnt(0)" ::: "memory");   // drain ONCE per block
    __syncthreads();

    // ---- compute: thread -> (col = tid&15, 8 channels from ch0)
    const int c   = tid & 15;
    const int ch0 = (tid >> 4) * 8;                    // 0,8,...,120

    const int col4g = blockIdx.x * TILE + c;
    const int b     = col4g / HW4;
    const int hw4   = col4g - b * HW4;
    float4* obase   = out + (size_t)b * BSTR4 + hw4;

    // initial window sum: planes ch0-8 .. ch0+8 (mod 128)
    float sx = 0.f, sy = 0.f, sz = 0.f, sw = 0.f;
#pragma unroll
    for (int j = -8; j <= 8; ++j) {
        const float4 v = lds[((ch0 + j) & 127) * TILE + c];
        sx = fmaf(v.x, v.x, sx);
        sy = fmaf(v.y, v.y, sy);
        sz = fmaf(v.z, v.z, sz);
        sw = fmaf(v.w, v.w, sw);
    }

#pragma unroll
    for (int i = 0; i < 8; ++i) {
        const int ch = ch0 + i;                        // <= 127, never wraps
        const float4 xc = lds[ch * TILE + c];          // numerator plane
        float4 o;
        o.x = xc.x * pow_m075(fmaf(sx, kAlphaOverR, 1.0f));
        o.y = xc.y * pow_m075(fmaf(sy, kAlphaOverR, 1.0f));
        o.z = xc.z * pow_m075(fmaf(sz, kAlphaOverR, 1.0f));
        o.w = xc.w * pow_m075(fmaf(sw, kAlphaOverR, 1.0f));
        obase[(size_t)ch * CSTR] = o;

        if (i < 7) {                                   // slide window mod 128
            const float4 a = lds[((ch + 9) & 127) * TILE + c];
            const float4 d = lds[((ch - 8) & 127) * TILE + c];
            sx += a.x * a.x - d.x * d.x;
            sy += a.y * a.y - d.y * d.y;
            sz += a.z * a.z - d.z * d.z;
            sw += a.w * a.w - d.w * d.w;
        }
    }
}

extern "C" void kernel_launch(void* const* d_in, const int* in_sizes, int n_in,
                              void* d_out, int out_size, void* d_ws, size_t ws_size,
                              hipStream_t stream) {
    const float4* x = (const float4*)d_in[0];   // [64,128,56,56] fp32
    // d_in[1] (inhiMat) is a constant circulant band — computed analytically, unused.
    float4* out = (float4*)d_out;

    // 3136 blocks x 256 threads; 32 KB LDS -> 5 blocks/CU (160 KB exactly),
    // 20 waves/CU. Amp 1.0 both directions; 5 desynchronized pipeline slots
    // keep the CU's load queue non-empty through compute/store phases.
    dim3 grid(NBLK);
    lrn_kernel<<<grid, 256, 0, stream>>>(x, out);
}

// Round 7
// 182.331 us; speedup vs baseline: 1.2129x; 1.0042x over previous
//
#include <hip/hip_runtime.h>

// LRN_19705309954750 — cross-channel banded LRN on [B=64, C=128, H=56, W=56] fp32.
// y[c] = sum_{d=-8..8} x[(c+d)%128]^2 ; out = x * (y*ALPHA/17 + 1)^(-0.75)
//
// R11 post-mortem: occupancy tracks block-slots (16%->31%) but BW doesn't
// (2.55 TB/s): __syncthreads + whole-block drain puts all waves of all
// co-launched blocks in LOCKSTEP phases -> HBM idles during collective
// compute. fillBufferAligned hits 6.7 TB/s at 10% occupancy in the same
// trace: the pipe needs decorrelated requests, not occupancy.
// (R8 re-diagnosis: its counted vmcnt waited on interleaved STORES --
// vmcnt counts stores -- store-retirement throttling, not compiler drains.)
// R12: wave-private one-shot staging, ZERO synchronization. Each wave owns a
// 12 KB LDS buffer (48 planes x 16 cols) = its 32-channel band +/-8 halo.
// 12 global_load_lds (unsinkable) -> per-wave vmcnt(0) (own loads only; no
// stores outstanding) -> compute from LDS -> stream stores. No barriers at
// all: 12 independent wave-pipelines/CU drift out of phase and keep the
// memory pipe fed continuously. Amp 1.5x cache-side, ~1.0 HBM via L3.
// Floor: (154+100) MB / 6.3 TB/s ~= 40 us.

#define HW4 784                  // float4 columns per plane (56*56/4)
#define CSTR HW4                 // float4 stride: channel plane
#define BSTR4 (128 * HW4)        // float4 stride: batch image
#define NCOL4 (64 * HW4)         // 50176 float4 columns total
#define TILE 16                  // float4 columns per block (one col-tile)
#define SEGC 32                  // channels per wave band
#define PLANES 48                // SEGC + 16 halo planes staged per wave
#define NBLK (NCOL4 / TILE)      // 3136 blocks

typedef __attribute__((address_space(3))) unsigned int lds_u32;
typedef __attribute__((address_space(1))) const unsigned int glb_u32;

__device__ __forceinline__ float pow_m075(float t) {
    // t in [1, ~1.01]; HW log2 + exp2 (~1 ulp each) — far inside 0.108 absmax
    return __builtin_amdgcn_exp2f(-0.75f * __builtin_amdgcn_logf(t));
}

__global__ __launch_bounds__(256) void lrn_kernel(const float4* __restrict__ x,
                                                  float4* __restrict__ out) {
    const float kAlphaOverR = 0.001f / 17.0f;

    // 4 waves x 48 planes x 16 cols x 16 B = 48 KB -> 3 blocks/CU, 12 waves/CU
    __shared__ float4 lds[4 * PLANES * TILE];

    const int tid  = threadIdx.x;
    const int lane = tid & 63;
    const int wave = tid >> 6;                 // 0..3 -> channel band 32*wave
    const int band = wave * SEGC;

    float4* buf = &lds[wave * (PLANES * TILE)];   // wave-PRIVATE buffer

    const int cl    = lane & 15;               // column within tile (stage & compute)
    const int g     = lane >> 4;               // 0..3: plane-sub (stage) / ch-group (compute)
    const int col4g = blockIdx.x * TILE + cl;  // global float4 column
    const int b     = col4g / HW4;
    const int hw4   = col4g - b * HW4;
    const float4* xbase = x + (size_t)b * BSTR4 + hw4;
    float4*       obase = out + (size_t)b * BSTR4 + hw4;

    // ---- stage own 48 planes: 12 insts, inst q -> buffer planes 4q..4q+3.
    //      lane l: plane 4q+g, col cl; LDS dest = uniform + lane*16 (linear ✓),
    //      global src per-lane (band-8+4q+g mod 128) ✓.
#pragma unroll
    for (int q = 0; q < 12; ++q) {
        const int ch = (band - 8 + 4 * q + g + 128) & 127;
        __builtin_amdgcn_global_load_lds((glb_u32*)(xbase + (size_t)ch * CSTR),
                                         (lds_u32*)&buf[q * 64], 16, 0, 0);
    }
    // Per-wave drain of OWN loads only (no stores outstanding, no barrier,
    // no other wave involved). Waves drift freely out of phase.
    asm volatile("s_waitcnt vmcnt(0)" ::: "memory");

    // ---- compute: thread = (col cl, channel group g): channels band+8g..band+8g+7
    //      buffer plane j holds channel band-8+j  ->  channel band+8g+i <=> j=8g+8+i
    float sx = 0.f, sy = 0.f, sz = 0.f, sw = 0.f;
#pragma unroll
    for (int j = 0; j < 17; ++j) {             // window for i=0: j = 8g .. 8g+16
        const float4 v = buf[(g * 8 + j) * TILE + cl];
        sx = fmaf(v.x, v.x, sx);
        sy = fmaf(v.y, v.y, sy);
        sz = fmaf(v.z, v.z, sz);
        sw = fmaf(v.w, v.w, sw);
    }

#pragma unroll
    for (int i = 0; i < 8; ++i) {
        const int j = g * 8 + 8 + i;                   // buffer plane of channel
        const float4 xc = buf[j * TILE + cl];          // numerator
        float4 o;
        o.x = xc.x * pow_m075(fmaf(sx, kAlphaOverR, 1.0f));
        o.y = xc.y * pow_m075(fmaf(sy, kAlphaOverR, 1.0f));
        o.z = xc.z * pow_m075(fmaf(sz, kAlphaOverR, 1.0f));
        o.w = xc.w * pow_m075(fmaf(sw, kAlphaOverR, 1.0f));
        obase[(size_t)(band + g * 8 + i) * CSTR] = o;  // ch in [0,128), no wrap

        if (i < 7) {                                   // slide: +j+9, -(j-8)
            const float4 a = buf[(j + 9) * TILE + cl];
            const float4 d = buf[(j - 8) * TILE + cl];
            sx += a.x * a.x - d.x * d.x;
            sy += a.y * a.y - d.y * d.y;
            sz += a.z * a.z - d.z * d.z;
            sw += a.w * a.w - d.w * d.w;
        }
    }
}

extern "C" void kernel_launch(void* const* d_in, const int* in_sizes, int n_in,
                              void* d_out, int out_size, void* d_ws, size_t ws_size,
                              hipStream_t stream) {
    const float4* x = (const float4*)d_in[0];   // [64,128,56,56] fp32
    // d_in[1] (inhiMat) is a constant circulant band — computed analytically, unused.
    float4* out = (float4*)d_out;

    // 3136 blocks x 256 threads, 48 KB LDS -> 3 blocks/CU, 12 waves/CU.
    // Each wave is a fully independent stage->drain->compute pipeline; no
    // block-level sync exists, so pipelines decorrelate and the CU's memory
    // queue stays non-empty.
    dim3 grid(NBLK);
    lrn_kernel<<<grid, 256, 0, stream>>>(x, out);
}